// Round 1
// baseline (10759.760 us; speedup 1.0000x reference)
//
#include <hip/hip_runtime.h>
#include <hip/hip_bf16.h>
#include <hip/hip_cooperative_groups.h>

namespace cg = cooperative_groups;

typedef __attribute__((ext_vector_type(8))) short bf16x8;
typedef __attribute__((ext_vector_type(4))) float f32x4;

#define NB 64
#define NT 512
#define ND 512
#define NU 512

__device__ __forceinline__ unsigned short f2bf(float f) {
  union { float f; unsigned int u; } v; v.f = f;
  unsigned int r = v.u + 0x7fffu + ((v.u >> 16) & 1u);
  return (unsigned short)(r >> 16);
}
__device__ __forceinline__ float bf2f(unsigned short h) {
  union { unsigned int u; float f; } v; v.u = ((unsigned int)h) << 16;
  return v.f;
}
__device__ __forceinline__ float sigm(float x) {
  return 1.f / (1.f + __expf(-x));
}
__device__ __forceinline__ float tanh_f(float x) {
  float ax = fminf(fabsf(x), 15.f);
  float e = __expf(2.f * ax);
  float t = (e - 1.f) / (e + 1.f);
  return copysignf(t, x);
}

// ---------------- prep kernels ----------------

// X fp32 -> bf16
__global__ void k_cvt_x(const float* __restrict__ X, unsigned short* __restrict__ Xb, int n) {
  int i = (blockIdx.x * 256 + threadIdx.x) * 4;
  if (i < n) {
    float4 v = *(const float4*)(X + i);
    ushort4 o;
    o.x = f2bf(v.x); o.y = f2bf(v.y); o.z = f2bf(v.z); o.w = f2bf(v.w);
    *(ushort4*)(Xb + i) = o;
  }
}

// WxcatT [c=2048][k=512] bf16, c = u*4 + gate, from x-part rows (512..1023) of W
__global__ void k_wx(const float* __restrict__ Wf, const float* __restrict__ Wi,
                     const float* __restrict__ Wc, const float* __restrict__ Wo,
                     unsigned short* __restrict__ Wt) {
  int idx = blockIdx.x * 256 + threadIdx.x;   // 2048*512 threads
  int c = idx >> 9, k = idx & 511;
  int gate = c & 3, u = c >> 2;
  const float* W = (gate == 0) ? Wf : (gate == 1) ? Wi : (gate == 2) ? Wc : Wo;
  Wt[idx] = f2bf(W[(512 + k) * 512 + u]);
}

// WhPack: per block j, B-frag order: chunk = ((j*16+ks)*2+cg)*64+lane, 8 bf16 per chunk
__global__ void k_whpack(const float* __restrict__ Wf, const float* __restrict__ Wi,
                         const float* __restrict__ Wc, const float* __restrict__ Wo,
                         unsigned short* __restrict__ P) {
  int chunk = blockIdx.x * 256 + threadIdx.x;   // 131072
  int lane = chunk & 63;
  int cgi = (chunk >> 6) & 1;
  int ks = (chunk >> 7) & 15;
  int j = chunk >> 11;
  int cl = cgi * 16 + (lane & 15);
  int u = j * 8 + (cl >> 2);
  int gate = cl & 3;
  const float* W = (gate == 0) ? Wf : (gate == 1) ? Wi : (gate == 2) ? Wc : Wo;
  int kb = ks * 32 + (lane >> 4) * 8;
  ushort4 lo, hi;
  lo.x = f2bf(W[(kb + 0) * 512 + u]); lo.y = f2bf(W[(kb + 1) * 512 + u]);
  lo.z = f2bf(W[(kb + 2) * 512 + u]); lo.w = f2bf(W[(kb + 3) * 512 + u]);
  hi.x = f2bf(W[(kb + 4) * 512 + u]); hi.y = f2bf(W[(kb + 5) * 512 + u]);
  hi.z = f2bf(W[(kb + 6) * 512 + u]); hi.w = f2bf(W[(kb + 7) * 512 + u]);
  *(ushort4*)(P + chunk * 8) = lo;
  *(ushort4*)(P + chunk * 8 + 4) = hi;
}

// ---------------- phase A: xproj = Xb @ WxcatT^T, output bf16 [32768][2048] ----------------

#define LDAP 72   // padded row stride (elems) to break bank conflicts

__global__ void __launch_bounds__(256)
k_gemm_xproj(const unsigned short* __restrict__ Xb,
             const unsigned short* __restrict__ Wt,
             unsigned short* __restrict__ xproj) {
  __shared__ unsigned short As[128 * LDAP];
  __shared__ unsigned short Bs[128 * LDAP];
  const int tid = threadIdx.x;
  const int bid = blockIdx.x;
  const int mt = bid >> 4;
  const int ntile = bid & 15;
  const int m0 = mt * 128, n0 = ntile * 128;
  const int lane = tid & 63, w = tid >> 6;
  const int wm = w >> 1, wn = w & 1;

  const unsigned short* aSrc = Xb + (long)(m0 + (tid >> 3)) * 512 + (tid & 7) * 8;
  const unsigned short* bSrc = Wt + (long)(n0 + (tid >> 3)) * 512 + (tid & 7) * 8;
  const int ldsRow = (tid >> 3);          // +c*32 per chunk
  const int ldsK = (tid & 7) * 8;

  f32x4 acc[4][4] = {};
  bf16x8 sa[4], sb[4];

#pragma unroll
  for (int c = 0; c < 4; c++) {
    sa[c] = *(const bf16x8*)(aSrc + (long)c * 32 * 512);
    sb[c] = *(const bf16x8*)(bSrc + (long)c * 32 * 512);
  }
  for (int kk = 0; kk < 8; kk++) {
    __syncthreads();
#pragma unroll
    for (int c = 0; c < 4; c++) {
      *(bf16x8*)(As + (c * 32 + ldsRow) * LDAP + ldsK) = sa[c];
      *(bf16x8*)(Bs + (c * 32 + ldsRow) * LDAP + ldsK) = sb[c];
    }
    __syncthreads();
    if (kk < 7) {
      const unsigned short* aS = aSrc + (kk + 1) * 64;
      const unsigned short* bS = bSrc + (kk + 1) * 64;
#pragma unroll
      for (int c = 0; c < 4; c++) {
        sa[c] = *(const bf16x8*)(aS + (long)c * 32 * 512);
        sb[c] = *(const bf16x8*)(bS + (long)c * 32 * 512);
      }
    }
#pragma unroll
    for (int ks = 0; ks < 2; ks++) {
      bf16x8 afr[4], bfr[4];
#pragma unroll
      for (int i = 0; i < 4; i++)
        afr[i] = *(const bf16x8*)(As + (wm * 64 + i * 16 + (lane & 15)) * LDAP + ks * 32 + (lane >> 4) * 8);
#pragma unroll
      for (int i = 0; i < 4; i++)
        bfr[i] = *(const bf16x8*)(Bs + (wn * 64 + i * 16 + (lane & 15)) * LDAP + ks * 32 + (lane >> 4) * 8);
#pragma unroll
      for (int i = 0; i < 4; i++)
#pragma unroll
        for (int jn = 0; jn < 4; jn++)
          acc[i][jn] = __builtin_amdgcn_mfma_f32_16x16x32_bf16(afr[i], bfr[jn], acc[i][jn], 0, 0, 0);
    }
  }
#pragma unroll
  for (int i = 0; i < 4; i++) {
    int row = m0 + wm * 64 + i * 16 + (lane >> 4) * 4;
#pragma unroll
    for (int jn = 0; jn < 4; jn++) {
      int col = n0 + wn * 64 + jn * 16 + (lane & 15);
#pragma unroll
      for (int r = 0; r < 4; r++)
        xproj[(long)(row + r) * 2048 + col] = f2bf(acc[i][jn][r]);
    }
  }
}

// ---------------- phase B: cooperative recurrence, 64 blocks x 256 threads ----------------

__global__ void __launch_bounds__(256)
k_lstm(const unsigned short* __restrict__ xproj,
       const unsigned short* __restrict__ WhP,
       unsigned short* __restrict__ Hp,
       const float* __restrict__ Bf, const float* __restrict__ Bi,
       const float* __restrict__ Bc, const float* __restrict__ Bo,
       float* __restrict__ out) {
  const int j = blockIdx.x;
  const int tid = threadIdx.x;
  const int lane = tid & 63;
  const int w = tid >> 6;

  __shared__ __align__(16) float Gbuf[64 * 36];
  __shared__ __align__(16) unsigned short Hbuf[64 * 8];

  // persistent weight B-frags in registers: 32 frags = 128 VGPRs
  bf16x8 bfrag[16][2];
#pragma unroll
  for (int ks = 0; ks < 16; ks++)
#pragma unroll
    for (int cgi = 0; cgi < 2; cgi++)
      bfrag[ks][cgi] = *(const bf16x8*)(WhP + ((((j * 16 + ks) * 2 + cgi) * 64 + lane) << 3));

  const int u = tid & 7;
  const int b0 = tid >> 3;    // batches b0 and b0+32
  float cA = 0.f, cB = 0.f;
  const float bF = Bf[j * 8 + u], bI = Bi[j * 8 + u];
  const float bC = Bc[j * 8 + u], bO = Bo[j * 8 + u];
  const unsigned short* xpA = xproj + (long)b0 * NT * 2048 + j * 32 + u * 4;
  const unsigned short* xpB = xpA + (long)32 * NT * 2048;
  float* outA = out + (long)b0 * NT * NU + j * 8 + u;
  float* outB = outA + (long)32 * NT * NU;

  unsigned short* hdst =
      Hp + ((((j >> 2) * 4 + (lane >> 4)) * 64 + (j & 3) * 16 + (lane & 15)) << 3);

  cg::grid_group grid = cg::this_grid();

  int cur = 0;
  for (int t = 0; t < NT; t++) {
    const unsigned short* hp = Hp + cur * 32768;
    bf16x8 af[16];
#pragma unroll
    for (int ks = 0; ks < 16; ks++)
      af[ks] = *(const bf16x8*)(hp + (((ks * 4 + w) * 64 + lane) << 3));
    ushort4 xa = *(const ushort4*)(xpA + (long)t * 2048);
    ushort4 xb = *(const ushort4*)(xpB + (long)t * 2048);

    f32x4 acc0 = {0.f, 0.f, 0.f, 0.f}, acc1 = {0.f, 0.f, 0.f, 0.f};
#pragma unroll
    for (int ks = 0; ks < 16; ks++) {
      acc0 = __builtin_amdgcn_mfma_f32_16x16x32_bf16(af[ks], bfrag[ks][0], acc0, 0, 0, 0);
      acc1 = __builtin_amdgcn_mfma_f32_16x16x32_bf16(af[ks], bfrag[ks][1], acc1, 0, 0, 0);
    }
    const int grow = w * 16 + (lane >> 4) * 4;
    const int gcol = lane & 15;
#pragma unroll
    for (int r = 0; r < 4; r++) {
      Gbuf[(grow + r) * 36 + gcol] = acc0[r];
      Gbuf[(grow + r) * 36 + 16 + gcol] = acc1[r];
    }
    __syncthreads();
    {
      float4 ga = *(const float4*)(Gbuf + b0 * 36 + u * 4);
      float4 gb = *(const float4*)(Gbuf + (b0 + 32) * 36 + u * 4);
      float f1 = sigm(ga.x + bf2f(xa.x) + bF);
      float i1 = sigm(ga.y + bf2f(xa.y) + bI);
      float g1 = tanh_f(ga.z + bf2f(xa.z) + bC);
      float o1 = sigm(ga.w + bf2f(xa.w) + bO);
      cA = f1 * cA + i1 * g1;
      float hA = o1 * tanh_f(cA);
      float f2 = sigm(gb.x + bf2f(xb.x) + bF);
      float i2 = sigm(gb.y + bf2f(xb.y) + bI);
      float g2 = tanh_f(gb.z + bf2f(xb.z) + bC);
      float o2 = sigm(gb.w + bf2f(xb.w) + bO);
      cB = f2 * cB + i2 * g2;
      float hB = o2 * tanh_f(cB);
      outA[(long)t * NU] = hA;
      outB[(long)t * NU] = hB;
      Hbuf[b0 * 8 + u] = f2bf(hA);
      Hbuf[(b0 + 32) * 8 + u] = f2bf(hB);
    }
    __syncthreads();
    if (w == 0) {
      ushort4 h0 = *(const ushort4*)(Hbuf + lane * 8);
      ushort4 h1 = *(const ushort4*)(Hbuf + lane * 8 + 4);
      unsigned short* dst = hdst + (cur ^ 1) * 32768;
      *(ushort4*)(dst) = h0;
      *(ushort4*)(dst + 4) = h1;
    }
    __threadfence();
    grid.sync();
    __threadfence();
    cur ^= 1;
  }
}

// ---------------- host ----------------

extern "C" void kernel_launch(void* const* d_in, const int* in_sizes, int n_in,
                              void* d_out, int out_size, void* d_ws, size_t ws_size,
                              hipStream_t stream) {
  const float* X  = (const float*)d_in[0];
  const float* Wf = (const float*)d_in[1];
  const float* Bf = (const float*)d_in[2];
  const float* Wi = (const float*)d_in[3];
  const float* Bi = (const float*)d_in[4];
  const float* Wc = (const float*)d_in[5];
  const float* Bc = (const float*)d_in[6];
  const float* Wo = (const float*)d_in[7];
  const float* Bo = (const float*)d_in[8];
  float* out = (float*)d_out;

  // workspace layout (bytes)
  const size_t XB_OFF  = 0;                       // 33,554,432
  const size_t WT_OFF  = 33554432;                // 2,097,152
  const size_t XP_OFF  = 35651584;                // 134,217,728
  const size_t WHP_OFF = 169869312;               // 2,097,152
  const size_t HP_OFF  = 171966464;               // 131,072
  const size_t NEEDED  = 172097536;
  if (ws_size < NEEDED) return;

  char* ws = (char*)d_ws;
  unsigned short* Xb    = (unsigned short*)(ws + XB_OFF);
  unsigned short* Wt    = (unsigned short*)(ws + WT_OFF);
  unsigned short* xproj = (unsigned short*)(ws + XP_OFF);
  unsigned short* WhP   = (unsigned short*)(ws + WHP_OFF);
  unsigned short* Hp    = (unsigned short*)(ws + HP_OFF);

  hipMemsetAsync(Hp, 0, 131072, stream);
  k_cvt_x<<<16384, 256, 0, stream>>>(X, Xb, NB * NT * ND);
  k_wx<<<4096, 256, 0, stream>>>(Wf, Wi, Wc, Wo, Wt);
  k_whpack<<<512, 256, 0, stream>>>(Wf, Wi, Wc, Wo, WhP);
  k_gemm_xproj<<<4096, 256, 0, stream>>>(Xb, Wt, xproj);

  const unsigned short* xp_a = xproj;
  const unsigned short* whp_a = WhP;
  unsigned short* hp_a = Hp;
  const float *bf_a = Bf, *bi_a = Bi, *bc_a = Bc, *bo_a = Bo;
  float* out_a = out;
  void* args[8] = {&xp_a, &whp_a, &hp_a, &bf_a, &bi_a, &bc_a, &bo_a, &out_a};
  hipLaunchCooperativeKernel((void*)k_lstm, dim3(64), dim3(256), args, 0, stream);
}

// Round 2
// 3913.222 us; speedup vs baseline: 2.7496x; 2.7496x over previous
//
#include <hip/hip_runtime.h>
#include <hip/hip_bf16.h>

typedef __attribute__((ext_vector_type(8))) short bf16x8;
typedef __attribute__((ext_vector_type(4))) float f32x4;

#define NB 64
#define NT 512
#define ND 512
#define NU 512

__device__ __forceinline__ unsigned short f2bf(float f) {
  union { float f; unsigned int u; } v; v.f = f;
  unsigned int r = v.u + 0x7fffu + ((v.u >> 16) & 1u);
  return (unsigned short)(r >> 16);
}
__device__ __forceinline__ float bf2f(unsigned short h) {
  union { unsigned int u; float f; } v; v.u = ((unsigned int)h) << 16;
  return v.f;
}
__device__ __forceinline__ float sigm(float x) {
  return 1.f / (1.f + __expf(-x));
}
__device__ __forceinline__ float tanh_f(float x) {
  float ax = fminf(fabsf(x), 15.f);
  float e = __expf(2.f * ax);
  float t = (e - 1.f) / (e + 1.f);
  return copysignf(t, x);
}

// ---------------- prep kernels ----------------

__global__ void k_cvt_x(const float* __restrict__ X, unsigned short* __restrict__ Xb, int n) {
  int i = (blockIdx.x * 256 + threadIdx.x) * 4;
  if (i < n) {
    float4 v = *(const float4*)(X + i);
    ushort4 o;
    o.x = f2bf(v.x); o.y = f2bf(v.y); o.z = f2bf(v.z); o.w = f2bf(v.w);
    *(ushort4*)(Xb + i) = o;
  }
}

// WxcatT [c=2048][k=512] bf16, c = u*4 + gate, from x-part rows (512..1023) of W
__global__ void k_wx(const float* __restrict__ Wf, const float* __restrict__ Wi,
                     const float* __restrict__ Wc, const float* __restrict__ Wo,
                     unsigned short* __restrict__ Wt) {
  int idx = blockIdx.x * 256 + threadIdx.x;   // 2048*512 threads
  int c = idx >> 9, k = idx & 511;
  int gate = c & 3, u = c >> 2;
  const float* W = (gate == 0) ? Wf : (gate == 1) ? Wi : (gate == 2) ? Wc : Wo;
  Wt[idx] = f2bf(W[(512 + k) * 512 + u]);
}

// WhPack: per block j, B-frag order: chunk = ((j*16+ks)*2+cg)*64+lane, 8 bf16 per chunk
__global__ void k_whpack(const float* __restrict__ Wf, const float* __restrict__ Wi,
                         const float* __restrict__ Wc, const float* __restrict__ Wo,
                         unsigned short* __restrict__ P) {
  int chunk = blockIdx.x * 256 + threadIdx.x;   // 131072
  int lane = chunk & 63;
  int cgi = (chunk >> 6) & 1;
  int ks = (chunk >> 7) & 15;
  int j = chunk >> 11;
  int cl = cgi * 16 + (lane & 15);
  int u = j * 8 + (cl >> 2);
  int gate = cl & 3;
  const float* W = (gate == 0) ? Wf : (gate == 1) ? Wi : (gate == 2) ? Wc : Wo;
  int kb = ks * 32 + (lane >> 4) * 8;
  ushort4 lo, hi;
  lo.x = f2bf(W[(kb + 0) * 512 + u]); lo.y = f2bf(W[(kb + 1) * 512 + u]);
  lo.z = f2bf(W[(kb + 2) * 512 + u]); lo.w = f2bf(W[(kb + 3) * 512 + u]);
  hi.x = f2bf(W[(kb + 4) * 512 + u]); hi.y = f2bf(W[(kb + 5) * 512 + u]);
  hi.z = f2bf(W[(kb + 6) * 512 + u]); hi.w = f2bf(W[(kb + 7) * 512 + u]);
  *(ushort4*)(P + chunk * 8) = lo;
  *(ushort4*)(P + chunk * 8 + 4) = hi;
}

// ---------------- phase A: xproj = Xb @ WxcatT^T, output bf16 [32768][2048] ----------------

#define LDAP 72   // padded row stride (elems) to break bank conflicts

__global__ void __launch_bounds__(256)
k_gemm_xproj(const unsigned short* __restrict__ Xb,
             const unsigned short* __restrict__ Wt,
             unsigned short* __restrict__ xproj) {
  __shared__ unsigned short As[128 * LDAP];
  __shared__ unsigned short Bs[128 * LDAP];
  const int tid = threadIdx.x;
  const int bid = blockIdx.x;
  const int mt = bid >> 4;
  const int ntile = bid & 15;
  const int m0 = mt * 128, n0 = ntile * 128;
  const int lane = tid & 63, w = tid >> 6;
  const int wm = w >> 1, wn = w & 1;

  const unsigned short* aSrc = Xb + (long)(m0 + (tid >> 3)) * 512 + (tid & 7) * 8;
  const unsigned short* bSrc = Wt + (long)(n0 + (tid >> 3)) * 512 + (tid & 7) * 8;
  const int ldsRow = (tid >> 3);          // +c*32 per chunk
  const int ldsK = (tid & 7) * 8;

  f32x4 acc[4][4] = {};
  bf16x8 sa[4], sb[4];

#pragma unroll
  for (int c = 0; c < 4; c++) {
    sa[c] = *(const bf16x8*)(aSrc + (long)c * 32 * 512);
    sb[c] = *(const bf16x8*)(bSrc + (long)c * 32 * 512);
  }
  for (int kk = 0; kk < 8; kk++) {
    __syncthreads();
#pragma unroll
    for (int c = 0; c < 4; c++) {
      *(bf16x8*)(As + (c * 32 + ldsRow) * LDAP + ldsK) = sa[c];
      *(bf16x8*)(Bs + (c * 32 + ldsRow) * LDAP + ldsK) = sb[c];
    }
    __syncthreads();
    if (kk < 7) {
      const unsigned short* aS = aSrc + (kk + 1) * 64;
      const unsigned short* bS = bSrc + (kk + 1) * 64;
#pragma unroll
      for (int c = 0; c < 4; c++) {
        sa[c] = *(const bf16x8*)(aS + (long)c * 32 * 512);
        sb[c] = *(const bf16x8*)(bS + (long)c * 32 * 512);
      }
    }
#pragma unroll
    for (int ks = 0; ks < 2; ks++) {
      bf16x8 afr[4], bfr[4];
#pragma unroll
      for (int i = 0; i < 4; i++)
        afr[i] = *(const bf16x8*)(As + (wm * 64 + i * 16 + (lane & 15)) * LDAP + ks * 32 + (lane >> 4) * 8);
#pragma unroll
      for (int i = 0; i < 4; i++)
        bfr[i] = *(const bf16x8*)(Bs + (wn * 64 + i * 16 + (lane & 15)) * LDAP + ks * 32 + (lane >> 4) * 8);
#pragma unroll
      for (int i = 0; i < 4; i++)
#pragma unroll
        for (int jn = 0; jn < 4; jn++)
          acc[i][jn] = __builtin_amdgcn_mfma_f32_16x16x32_bf16(afr[i], bfr[jn], acc[i][jn], 0, 0, 0);
    }
  }
#pragma unroll
  for (int i = 0; i < 4; i++) {
    int row = m0 + wm * 64 + i * 16 + (lane >> 4) * 4;
#pragma unroll
    for (int jn = 0; jn < 4; jn++) {
      int col = n0 + wn * 64 + jn * 16 + (lane & 15);
#pragma unroll
      for (int r = 0; r < 4; r++)
        xproj[(long)(row + r) * 2048 + col] = f2bf(acc[i][jn][r]);
    }
  }
}

// ---------------- phase B: recurrence, 64 blocks x 256 threads, flag-based sync ----------------

__global__ void __launch_bounds__(256)
k_lstm(const unsigned short* __restrict__ xproj,
       const unsigned short* __restrict__ WhP,
       unsigned short* __restrict__ Hp,
       unsigned int* __restrict__ flags,
       const float* __restrict__ Bf, const float* __restrict__ Bi,
       const float* __restrict__ Bc, const float* __restrict__ Bo,
       float* __restrict__ out) {
  const int j = blockIdx.x;
  const int tid = threadIdx.x;
  const int lane = tid & 63;
  const int w = tid >> 6;

  __shared__ __align__(16) float Gbuf[64 * 36];
  __shared__ __align__(16) unsigned short Hbuf[64 * 8];

  // persistent weight B-frags in registers: 32 frags = 128 VGPRs
  bf16x8 bfrag[16][2];
#pragma unroll
  for (int ks = 0; ks < 16; ks++)
#pragma unroll
    for (int cgi = 0; cgi < 2; cgi++)
      bfrag[ks][cgi] = *(const bf16x8*)(WhP + ((((j * 16 + ks) * 2 + cgi) * 64 + lane) << 3));

  const int u = tid & 7;
  const int b0 = tid >> 3;    // batches b0 and b0+32
  float cA = 0.f, cB = 0.f;
  const float bF = Bf[j * 8 + u], bI = Bi[j * 8 + u];
  const float bC = Bc[j * 8 + u], bO = Bo[j * 8 + u];
  const unsigned short* xpA = xproj + (long)b0 * NT * 2048 + j * 32 + u * 4;
  const unsigned short* xpB = xpA + (long)32 * NT * 2048;
  float* outA = out + (long)b0 * NT * NU + j * 8 + u;
  float* outB = outA + (long)32 * NT * NU;

  unsigned short* hdst =
      Hp + ((((j >> 2) * 4 + (lane >> 4)) * 64 + (j & 3) * 16 + (lane & 15)) << 3);

  const unsigned int* myflag = flags + lane * 16;  // lane l watches block l (64B stride)

  for (int t = 0; t < NT; t++) {
    // xproj loads are independent of h_t: issue before the poll so they overlap the wait
    ushort4 xa = *(const ushort4*)(xpA + (long)t * 2048);
    ushort4 xb = *(const ushort4*)(xpB + (long)t * 2048);

    // wave-parallel wait for all 64 h_t slices (flag[j] == t means block j published h_t)
    if (t > 0) {
      while (!__all(__hip_atomic_load(myflag, __ATOMIC_RELAXED,
                                      __HIP_MEMORY_SCOPE_AGENT) >= (unsigned)t)) {
      }
      __builtin_amdgcn_fence(__ATOMIC_ACQUIRE, "agent");
    }

    const unsigned short* hp = Hp + (t & 1) * 32768;
    bf16x8 af[16];
#pragma unroll
    for (int ks = 0; ks < 16; ks++)
      af[ks] = *(const bf16x8*)(hp + (((ks * 4 + w) * 64 + lane) << 3));

    f32x4 acc0 = {0.f, 0.f, 0.f, 0.f}, acc1 = {0.f, 0.f, 0.f, 0.f};
#pragma unroll
    for (int ks = 0; ks < 16; ks++) {
      acc0 = __builtin_amdgcn_mfma_f32_16x16x32_bf16(af[ks], bfrag[ks][0], acc0, 0, 0, 0);
      acc1 = __builtin_amdgcn_mfma_f32_16x16x32_bf16(af[ks], bfrag[ks][1], acc1, 0, 0, 0);
    }
    const int grow = w * 16 + (lane >> 4) * 4;
    const int gcol = lane & 15;
#pragma unroll
    for (int r = 0; r < 4; r++) {
      Gbuf[(grow + r) * 36 + gcol] = acc0[r];
      Gbuf[(grow + r) * 36 + 16 + gcol] = acc1[r];
    }
    __syncthreads();
    {
      float4 ga = *(const float4*)(Gbuf + b0 * 36 + u * 4);
      float4 gb = *(const float4*)(Gbuf + (b0 + 32) * 36 + u * 4);
      float f1 = sigm(ga.x + bf2f(xa.x) + bF);
      float i1 = sigm(ga.y + bf2f(xa.y) + bI);
      float g1 = tanh_f(ga.z + bf2f(xa.z) + bC);
      float o1 = sigm(ga.w + bf2f(xa.w) + bO);
      cA = f1 * cA + i1 * g1;
      float hA = o1 * tanh_f(cA);
      float f2 = sigm(gb.x + bf2f(xb.x) + bF);
      float i2 = sigm(gb.y + bf2f(xb.y) + bI);
      float g2 = tanh_f(gb.z + bf2f(xb.z) + bC);
      float o2 = sigm(gb.w + bf2f(xb.w) + bO);
      cB = f2 * cB + i2 * g2;
      float hB = o2 * tanh_f(cB);
      outA[(long)t * NU] = hA;
      outB[(long)t * NU] = hB;
      Hbuf[b0 * 8 + u] = f2bf(hA);
      Hbuf[(b0 + 32) * 8 + u] = f2bf(hB);
    }
    __syncthreads();
    if (w == 0) {
      ushort4 h0 = *(const ushort4*)(Hbuf + lane * 8);
      ushort4 h1 = *(const ushort4*)(Hbuf + lane * 8 + 4);
      unsigned short* dst = hdst + ((t + 1) & 1) * 32768;
      *(ushort4*)(dst) = h0;
      *(ushort4*)(dst + 4) = h1;
      if (lane == 0) {
        // release covers this wave's h stores (vmcnt drain + L2 writeback)
        __hip_atomic_store(flags + j * 16, (unsigned)(t + 1), __ATOMIC_RELEASE,
                           __HIP_MEMORY_SCOPE_AGENT);
      }
    }
  }
}

// ---------------- host ----------------

extern "C" void kernel_launch(void* const* d_in, const int* in_sizes, int n_in,
                              void* d_out, int out_size, void* d_ws, size_t ws_size,
                              hipStream_t stream) {
  const float* X  = (const float*)d_in[0];
  const float* Wf = (const float*)d_in[1];
  const float* Bf = (const float*)d_in[2];
  const float* Wi = (const float*)d_in[3];
  const float* Bi = (const float*)d_in[4];
  const float* Wc = (const float*)d_in[5];
  const float* Bc = (const float*)d_in[6];
  const float* Wo = (const float*)d_in[7];
  const float* Bo = (const float*)d_in[8];
  float* out = (float*)d_out;

  // workspace layout (bytes)
  const size_t XB_OFF  = 0;                       // 33,554,432
  const size_t WT_OFF  = 33554432;                // 2,097,152
  const size_t XP_OFF  = 35651584;                // 134,217,728
  const size_t WHP_OFF = 169869312;               // 2,097,152
  const size_t HP_OFF  = 171966464;               // 131,072
  const size_t FL_OFF  = 172097536;               // 4,096 (64 flags, 64B apart)
  const size_t NEEDED  = 172101632;
  if (ws_size < NEEDED) return;

  char* ws = (char*)d_ws;
  unsigned short* Xb    = (unsigned short*)(ws + XB_OFF);
  unsigned short* Wt    = (unsigned short*)(ws + WT_OFF);
  unsigned short* xproj = (unsigned short*)(ws + XP_OFF);
  unsigned short* WhP   = (unsigned short*)(ws + WHP_OFF);
  unsigned short* Hp    = (unsigned short*)(ws + HP_OFF);
  unsigned int*   flags = (unsigned int*)(ws + FL_OFF);

  hipMemsetAsync(Hp, 0, 131072 + 4096, stream);   // Hp + flags are contiguous
  k_cvt_x<<<16384, 256, 0, stream>>>(X, Xb, NB * NT * ND);
  k_wx<<<4096, 256, 0, stream>>>(Wf, Wi, Wc, Wo, Wt);
  k_whpack<<<512, 256, 0, stream>>>(Wf, Wi, Wc, Wo, WhP);
  k_gemm_xproj<<<4096, 256, 0, stream>>>(Xb, Wt, xproj);

  const unsigned short* xp_a = xproj;
  const unsigned short* whp_a = WhP;
  unsigned short* hp_a = Hp;
  unsigned int* fl_a = flags;
  const float *bf_a = Bf, *bi_a = Bi, *bc_a = Bc, *bo_a = Bo;
  float* out_a = out;
  void* args[9] = {&xp_a, &whp_a, &hp_a, &fl_a, &bf_a, &bi_a, &bc_a, &bo_a, &out_a};
  hipLaunchCooperativeKernel((void*)k_lstm, dim3(64), dim3(256), args, 0, stream);
}

// Round 3
// 3083.977 us; speedup vs baseline: 3.4889x; 1.2689x over previous
//
#include <hip/hip_runtime.h>
#include <hip/hip_bf16.h>

typedef __attribute__((ext_vector_type(8))) short bf16x8;
typedef __attribute__((ext_vector_type(4))) float f32x4;

#define NB 64
#define NT 512
#define ND 512
#define NU 512

__device__ __forceinline__ unsigned short f2bf(float f) {
  union { float f; unsigned int u; } v; v.f = f;
  unsigned int r = v.u + 0x7fffu + ((v.u >> 16) & 1u);
  return (unsigned short)(r >> 16);
}
__device__ __forceinline__ float bf2f(unsigned short h) {
  union { unsigned int u; float f; } v; v.u = ((unsigned int)h) << 16;
  return v.f;
}
__device__ __forceinline__ float sigm(float x) {
  return 1.f / (1.f + __expf(-x));
}
__device__ __forceinline__ float tanh_f(float x) {
  float ax = fminf(fabsf(x), 15.f);
  float e = __expf(2.f * ax);
  float t = (e - 1.f) / (e + 1.f);
  return copysignf(t, x);
}

// ---------------- prep kernels ----------------

__global__ void k_cvt_x(const float* __restrict__ X, unsigned short* __restrict__ Xb, int n) {
  int i = (blockIdx.x * 256 + threadIdx.x) * 4;
  if (i < n) {
    float4 v = *(const float4*)(X + i);
    ushort4 o;
    o.x = f2bf(v.x); o.y = f2bf(v.y); o.z = f2bf(v.z); o.w = f2bf(v.w);
    *(ushort4*)(Xb + i) = o;
  }
}

// WxcatT [c=2048][k=512] bf16, c = u*4 + gate, from x-part rows (512..1023) of W
__global__ void k_wx(const float* __restrict__ Wf, const float* __restrict__ Wi,
                     const float* __restrict__ Wc, const float* __restrict__ Wo,
                     unsigned short* __restrict__ Wt) {
  int idx = blockIdx.x * 256 + threadIdx.x;   // 2048*512 threads
  int c = idx >> 9, k = idx & 511;
  int gate = c & 3, u = c >> 2;
  const float* W = (gate == 0) ? Wf : (gate == 1) ? Wi : (gate == 2) ? Wc : Wo;
  Wt[idx] = f2bf(W[(512 + k) * 512 + u]);
}

// WhPack: per block j, B-frag order: chunk = ((j*16+ks)*2+cg)*64+lane, 8 bf16 per chunk
__global__ void k_whpack(const float* __restrict__ Wf, const float* __restrict__ Wi,
                         const float* __restrict__ Wc, const float* __restrict__ Wo,
                         unsigned short* __restrict__ P) {
  int chunk = blockIdx.x * 256 + threadIdx.x;   // 131072
  int lane = chunk & 63;
  int cgi = (chunk >> 6) & 1;
  int ks = (chunk >> 7) & 15;
  int j = chunk >> 11;
  int cl = cgi * 16 + (lane & 15);
  int u = j * 8 + (cl >> 2);
  int gate = cl & 3;
  const float* W = (gate == 0) ? Wf : (gate == 1) ? Wi : (gate == 2) ? Wc : Wo;
  int kb = ks * 32 + (lane >> 4) * 8;
  ushort4 lo, hi;
  lo.x = f2bf(W[(kb + 0) * 512 + u]); lo.y = f2bf(W[(kb + 1) * 512 + u]);
  lo.z = f2bf(W[(kb + 2) * 512 + u]); lo.w = f2bf(W[(kb + 3) * 512 + u]);
  hi.x = f2bf(W[(kb + 4) * 512 + u]); hi.y = f2bf(W[(kb + 5) * 512 + u]);
  hi.z = f2bf(W[(kb + 6) * 512 + u]); hi.w = f2bf(W[(kb + 7) * 512 + u]);
  *(ushort4*)(P + chunk * 8) = lo;
  *(ushort4*)(P + chunk * 8 + 4) = hi;
}

// ---------------- phase A: xproj = Xb @ WxcatT^T, output bf16 [32768][2048] ----------------

#define LDAP 72   // padded row stride (elems) to break bank conflicts

__global__ void __launch_bounds__(256)
k_gemm_xproj(const unsigned short* __restrict__ Xb,
             const unsigned short* __restrict__ Wt,
             unsigned short* __restrict__ xproj) {
  __shared__ unsigned short As[128 * LDAP];
  __shared__ unsigned short Bs[128 * LDAP];
  const int tid = threadIdx.x;
  const int bid = blockIdx.x;
  const int mt = bid >> 4;
  const int ntile = bid & 15;
  const int m0 = mt * 128, n0 = ntile * 128;
  const int lane = tid & 63, w = tid >> 6;
  const int wm = w >> 1, wn = w & 1;

  const unsigned short* aSrc = Xb + (long)(m0 + (tid >> 3)) * 512 + (tid & 7) * 8;
  const unsigned short* bSrc = Wt + (long)(n0 + (tid >> 3)) * 512 + (tid & 7) * 8;
  const int ldsRow = (tid >> 3);          // +c*32 per chunk
  const int ldsK = (tid & 7) * 8;

  f32x4 acc[4][4] = {};
  bf16x8 sa[4], sb[4];

#pragma unroll
  for (int c = 0; c < 4; c++) {
    sa[c] = *(const bf16x8*)(aSrc + (long)c * 32 * 512);
    sb[c] = *(const bf16x8*)(bSrc + (long)c * 32 * 512);
  }
  for (int kk = 0; kk < 8; kk++) {
    __syncthreads();
#pragma unroll
    for (int c = 0; c < 4; c++) {
      *(bf16x8*)(As + (c * 32 + ldsRow) * LDAP + ldsK) = sa[c];
      *(bf16x8*)(Bs + (c * 32 + ldsRow) * LDAP + ldsK) = sb[c];
    }
    __syncthreads();
    if (kk < 7) {
      const unsigned short* aS = aSrc + (kk + 1) * 64;
      const unsigned short* bS = bSrc + (kk + 1) * 64;
#pragma unroll
      for (int c = 0; c < 4; c++) {
        sa[c] = *(const bf16x8*)(aS + (long)c * 32 * 512);
        sb[c] = *(const bf16x8*)(bS + (long)c * 32 * 512);
      }
    }
#pragma unroll
    for (int ks = 0; ks < 2; ks++) {
      bf16x8 afr[4], bfr[4];
#pragma unroll
      for (int i = 0; i < 4; i++)
        afr[i] = *(const bf16x8*)(As + (wm * 64 + i * 16 + (lane & 15)) * LDAP + ks * 32 + (lane >> 4) * 8);
#pragma unroll
      for (int i = 0; i < 4; i++)
        bfr[i] = *(const bf16x8*)(Bs + (wn * 64 + i * 16 + (lane & 15)) * LDAP + ks * 32 + (lane >> 4) * 8);
#pragma unroll
      for (int i = 0; i < 4; i++)
#pragma unroll
        for (int jn = 0; jn < 4; jn++)
          acc[i][jn] = __builtin_amdgcn_mfma_f32_16x16x32_bf16(afr[i], bfr[jn], acc[i][jn], 0, 0, 0);
    }
  }
#pragma unroll
  for (int i = 0; i < 4; i++) {
    int row = m0 + wm * 64 + i * 16 + (lane >> 4) * 4;
#pragma unroll
    for (int jn = 0; jn < 4; jn++) {
      int col = n0 + wn * 64 + jn * 16 + (lane & 15);
#pragma unroll
      for (int r = 0; r < 4; r++)
        xproj[(long)(row + r) * 2048 + col] = f2bf(acc[i][jn][r]);
    }
  }
}

// ---------------- phase B: recurrence, 64 blocks x 256 threads ----------------
// Per-wave decoupled pipelines: wave w of block j produces h[batches w*16..w*16+16)
// [units j*8..j*8+8), stores them as agent-scope (sc1, MALL-coherent) atomic stores,
// drains vmcnt, publishes per-wave flag. Consumer wave w polls the 64 flags of
// plane w, acquires (buffer_inv), loads h, MFMAs. No __syncthreads in the loop.

__device__ __forceinline__ float4 quad_transpose(f32x4 v, int g) {
  // v[r] = M[r][g] within a 4-lane quad; returns y[c] = M[g][c].
  const bool odd = g & 1;
  float s0 = odd ? v[0] : v[1];
  float s1 = odd ? v[2] : v[3];
  float r0 = __shfl_xor(s0, 1, 64);
  float r1 = __shfl_xor(s1, 1, 64);
  float X0 = odd ? r0 : v[0];
  float X1 = odd ? v[1] : r0;
  float X2 = odd ? r1 : v[2];
  float X3 = odd ? v[3] : r1;
  const bool hi = g & 2;
  float t0 = hi ? X0 : X2;
  float t1 = hi ? X1 : X3;
  float q0 = __shfl_xor(t0, 2, 64);
  float q1 = __shfl_xor(t1, 2, 64);
  float4 y;
  y.x = hi ? q0 : X0;
  y.y = hi ? q1 : X1;
  y.z = hi ? X2 : q0;
  y.w = hi ? X3 : q1;
  return y;
}

__global__ void __launch_bounds__(256)
k_lstm(const unsigned short* __restrict__ xproj,
       const unsigned short* __restrict__ WhP,
       unsigned short* __restrict__ Hp,
       unsigned int* __restrict__ flags,
       const float* __restrict__ Bf, const float* __restrict__ Bi,
       const float* __restrict__ Bc, const float* __restrict__ Bo,
       float* __restrict__ out) {
  const int j = blockIdx.x;
  const int tid = threadIdx.x;
  const int lane = tid & 63;
  const int w = tid >> 6;

  // persistent weight B-frags in registers: 32 frags = 128 regs (AGPR-eligible)
  bf16x8 bfrag[16][2];
#pragma unroll
  for (int ks = 0; ks < 16; ks++)
#pragma unroll
    for (int cgi = 0; cgi < 2; cgi++)
      bfrag[ks][cgi] = *(const bf16x8*)(WhP + ((((j * 16 + ks) * 2 + cgi) * 64 + lane) << 3));

  // thread's (batch, unit) ownership after the quad transpose
  const int g = lane & 3;
  const int up = (lane & 15) >> 2;                  // u' in [0,4)
  const int b = w * 16 + ((lane >> 4) << 2) + g;    // batch
  const int U0 = j * 8 + up;                        // unit for acc0; acc1 -> U0+4

  float c0 = 0.f, c1 = 0.f;
  const float bF0 = Bf[U0], bI0 = Bi[U0], bC0 = Bc[U0], bO0 = Bo[U0];
  const float bF1 = Bf[U0 + 4], bI1 = Bi[U0 + 4], bC1 = Bc[U0 + 4], bO1 = Bo[U0 + 4];

  const unsigned short* xp0 = xproj + (long)b * NT * 2048 + j * 32 + up * 4;
  float* out0 = out + (long)b * NT * NU + U0;

  // h store chunk (A-frag layout): ((ks*4 + w)*64 + (b&15) + ((j&3)<<4)) * 8 + e
  const int chunk = ((j >> 2) * 4 + w) * 64 + (b & 15) + ((j & 3) << 4);
  unsigned short* hdst0 = Hp + (chunk << 3) + up;     // e = up; +4 for U0+4

  unsigned int* pubflag = flags + (j * 4 + w) * 16;
  const unsigned int* pollbase = flags + (lane * 4 + w) * 16;  // lane l -> block l, plane w

  for (int t = 0; t < NT; t++) {
    // xproj loads are independent of h_t: issue before the poll to overlap the wait
    ushort4 xa = *(const ushort4*)(xp0 + (long)t * 2048);
    ushort4 xb = *(const ushort4*)(xp0 + (long)t * 2048 + 16);

    if (t > 0) {
      while (!__all(__hip_atomic_load(pollbase, __ATOMIC_RELAXED,
                                      __HIP_MEMORY_SCOPE_AGENT) >= (unsigned)t)) {
      }
      __builtin_amdgcn_fence(__ATOMIC_ACQUIRE, "agent");  // buffer_inv: drop stale h lines
    }

    const unsigned short* hp = Hp + (t & 1) * 32768;
    bf16x8 af[16];
#pragma unroll
    for (int ks = 0; ks < 16; ks++)
      af[ks] = *(const bf16x8*)(hp + (((ks * 4 + w) * 64 + lane) << 3));

    f32x4 acc0 = {0.f, 0.f, 0.f, 0.f}, acc1 = {0.f, 0.f, 0.f, 0.f};
#pragma unroll
    for (int ks = 0; ks < 16; ks++) {
      acc0 = __builtin_amdgcn_mfma_f32_16x16x32_bf16(af[ks], bfrag[ks][0], acc0, 0, 0, 0);
      acc1 = __builtin_amdgcn_mfma_f32_16x16x32_bf16(af[ks], bfrag[ks][1], acc1, 0, 0, 0);
    }

    // in-register gate exchange: 4x4 transpose within each quad
    float4 G0 = quad_transpose(acc0, g);
    float4 G1 = quad_transpose(acc1, g);

    float f0 = sigm(G0.x + bf2f(xa.x) + bF0);
    float i0 = sigm(G0.y + bf2f(xa.y) + bI0);
    float g0 = tanh_f(G0.z + bf2f(xa.z) + bC0);
    float o0 = sigm(G0.w + bf2f(xa.w) + bO0);
    c0 = f0 * c0 + i0 * g0;
    float h0 = o0 * tanh_f(c0);
    float f1 = sigm(G1.x + bf2f(xb.x) + bF1);
    float i1 = sigm(G1.y + bf2f(xb.y) + bI1);
    float g1 = tanh_f(G1.z + bf2f(xb.z) + bC1);
    float o1 = sigm(G1.w + bf2f(xb.w) + bO1);
    c1 = f1 * c1 + i1 * g1;
    float h1 = o1 * tanh_f(c1);

    // publish h (agent-scope write-through -> MALL, never dirty in L2)
    unsigned short* dst = hdst0 + ((t + 1) & 1) * 32768;
    __hip_atomic_store(dst, f2bf(h0), __ATOMIC_RELAXED, __HIP_MEMORY_SCOPE_AGENT);
    __hip_atomic_store(dst + 4, f2bf(h1), __ATOMIC_RELAXED, __HIP_MEMORY_SCOPE_AGENT);
    asm volatile("s_waitcnt vmcnt(0)" ::: "memory");   // h acked at coherence point
    if (lane == 0)
      __hip_atomic_store(pubflag, (unsigned)(t + 1), __ATOMIC_RELAXED,
                         __HIP_MEMORY_SCOPE_AGENT);

    // out stores AFTER the release: HBM ack rides in the shadow of the next step
    out0[(long)t * NU] = h0;
    out0[(long)t * NU + 4] = h1;
  }
}

// ---------------- host ----------------

extern "C" void kernel_launch(void* const* d_in, const int* in_sizes, int n_in,
                              void* d_out, int out_size, void* d_ws, size_t ws_size,
                              hipStream_t stream) {
  const float* X  = (const float*)d_in[0];
  const float* Wf = (const float*)d_in[1];
  const float* Bf = (const float*)d_in[2];
  const float* Wi = (const float*)d_in[3];
  const float* Bi = (const float*)d_in[4];
  const float* Wc = (const float*)d_in[5];
  const float* Bc = (const float*)d_in[6];
  const float* Wo = (const float*)d_in[7];
  const float* Bo = (const float*)d_in[8];
  float* out = (float*)d_out;

  // workspace layout (bytes). Hp+flags live in the Xb region (dead after the
  // x-projection GEMM); their memset is stream-ordered after k_gemm_xproj.
  const size_t XB_OFF  = 0;                       // 33,554,432 (Xb; later Hp+flags)
  const size_t HP_OFF  = 0;                       // 131,072   (2x 64KB ping-pong)
  const size_t FL_OFF  = 131072;                  // 16,384    (256 flags, 64B apart)
  const size_t WT_OFF  = 33554432;                // 2,097,152
  const size_t XP_OFF  = 35651584;                // 134,217,728
  const size_t WHP_OFF = 169869312;               // 2,097,152
  const size_t NEEDED  = 171966464;
  if (ws_size < NEEDED) return;

  char* ws = (char*)d_ws;
  unsigned short* Xb    = (unsigned short*)(ws + XB_OFF);
  unsigned short* Wt    = (unsigned short*)(ws + WT_OFF);
  unsigned short* xproj = (unsigned short*)(ws + XP_OFF);
  unsigned short* WhP   = (unsigned short*)(ws + WHP_OFF);
  unsigned short* Hp    = (unsigned short*)(ws + HP_OFF);
  unsigned int*   flags = (unsigned int*)(ws + FL_OFF);

  k_cvt_x<<<16384, 256, 0, stream>>>(X, Xb, NB * NT * ND);
  k_wx<<<4096, 256, 0, stream>>>(Wf, Wi, Wc, Wo, Wt);
  k_whpack<<<512, 256, 0, stream>>>(Wf, Wi, Wc, Wo, WhP);
  k_gemm_xproj<<<4096, 256, 0, stream>>>(Xb, Wt, xproj);
  hipMemsetAsync(ws + HP_OFF, 0, 131072 + 16384, stream);  // after GEMM: Xb is dead

  const unsigned short* xp_a = xproj;
  const unsigned short* whp_a = WhP;
  unsigned short* hp_a = Hp;
  unsigned int* fl_a = flags;
  const float *bf_a = Bf, *bi_a = Bi, *bc_a = Bc, *bo_a = Bo;
  float* out_a = out;
  void* args[9] = {&xp_a, &whp_a, &hp_a, &fl_a, &bf_a, &bi_a, &bc_a, &bo_a, &out_a};
  hipLaunchCooperativeKernel((void*)k_lstm, dim3(64), dim3(256), args, 0, stream);
}